// Round 22
// baseline (121.152 us; speedup 1.0000x reference)
//
#include <hip/hip_runtime.h>
#include <hip/hip_bf16.h>
#include <math.h>

#define BATCH   2048
#define NFIELDS 32
#define EMBED   64
#define NPAIRS  496

typedef __attribute__((ext_vector_type(8))) short bf16x8;
typedef __attribute__((ext_vector_type(4))) float f32x4;

__device__ __forceinline__ unsigned short f2bf(float x) {
    unsigned int u = __float_as_uint(x);
    unsigned int r = 0x7fffu + ((u >> 16) & 1u);
    return (unsigned short)((u + r) >> 16);
}
__device__ __forceinline__ float bf2f(unsigned short b) {
    return __uint_as_float(((unsigned int)b) << 16);
}
__device__ __forceinline__ bf16x8 cvt8(const float* p) {
    float4 v0 = *(const float4*)p;
    float4 v1 = *(const float4*)(p + 4);
    bf16x8 o;
    o[0]=(short)f2bf(v0.x); o[1]=(short)f2bf(v0.y); o[2]=(short)f2bf(v0.z); o[3]=(short)f2bf(v0.w);
    o[4]=(short)f2bf(v1.x); o[5]=(short)f2bf(v1.y); o[6]=(short)f2bf(v1.z); o[7]=(short)f2bf(v1.w);
    return o;
}

// Prepass with TRANSPOSE (kills L2 line-over-fetch in main):
//  embT[f][b][j] bf16  (batch becomes the fast-varying axis for fixed field)
//  K'  [p][blk=nt*2+ks][col][quad][8] bf16 (fragment-order: kfr reads coalesced)
// Both writes are linear in thread id; reads are 64B-line-efficient.
__global__ __launch_bounds__(256) void convert_prepass(
    const float* __restrict__ emb, const float* __restrict__ kern,
    unsigned short* __restrict__ embT, unsigned short* __restrict__ kernB)
{
    const int EMBT4 = BATCH * NFIELDS * EMBED / 4;  // 1048576
    const int KER4  = EMBED * NPAIRS * EMBED / 4;   // 507904
    int t = blockIdx.x * blockDim.x + threadIdx.x;
    if (t < EMBT4) {
        int j4   = t & 15;          // j/4
        int rest = t >> 4;          // f*2048 + b
        int b = rest & 2047;
        int f = rest >> 11;
        float4 v = *(const float4*)(emb + ((size_t)b * NFIELDS + f) * EMBED + j4 * 4);
        ushort4 o;
        o.x = f2bf(v.x); o.y = f2bf(v.y); o.z = f2bf(v.z); o.w = f2bf(v.w);
        *(ushort4*)(embT + (size_t)t * 4) = o;      // == (f*2048+b)*64 + j4*4
    } else if (t < EMBT4 + KER4) {
        int u = t - EMBT4;
        int g    = u & 1;           // half of the 8-elem group
        int quad = (u >> 1) & 3;
        int col  = (u >> 3) & 15;
        int blk  = (u >> 7) & 7;    // nt*2 + ks
        int p    = u >> 10;         // 0..495
        int i = (blk >> 1) * 16 + col;
        int j = (blk & 1) * 32 + quad * 8 + g * 4;
        float4 v = *(const float4*)(kern + (size_t)i * (NPAIRS*EMBED) + (size_t)p * EMBED + j);
        ushort4 o;
        o.x = f2bf(v.x); o.y = f2bf(v.y); o.z = f2bf(v.z); o.w = f2bf(v.w);
        *(ushort4*)(kernB + (size_t)u * 4) = o;     // == p*4096 + blk*512 + col*32 + quad*8 + g*4
    }
}

// Main: 992 blocks = 124 chunks x 8 batch-tiles(256). Wave w owns pair chunk*4+w,
// 16 iterations of 16 batches. Direct VGPR loads from TRANSPOSED layouts:
// every access instruction touches full 64B lines (bfr0/bfr1 = the two half-lines
// of 16 contiguous batch rows; q's 4 reads share one 2KB window). No LDS staging.
// Compute/reduce/epilogue body is verbatim R12 (correctness-proven).
// bt = bid&7 pins each 256-batch slice to one XCD's L2.
template<bool PRE>
__global__ __launch_bounds__(256, 4) void opn_fused(
    const void* __restrict__ embP, const void* __restrict__ kernP,
    const float* __restrict__ embF, float* __restrict__ out)
{
    const int bid   = blockIdx.x;
    const int chunk = bid >> 3;            // 0..123
    const int bt    = bid & 7;             // 0..7 == XCD id (round-robin dispatch)

    const int tid  = threadIdx.x;
    const int wave = tid >> 6, lane = tid & 63;
    const int col  = lane & 15, quad = lane >> 4;
    const int pair = chunk * 4 + wave;

    // closed-form triu k=1 decode (R12-proven)
    int r;
    {
        float sq = sqrtf((float)(3969 - 8 * pair));   // 3969 = 63^2
        r = (int)((63.0f - sq) * 0.5f);
        if (r > 0 && r * (63 - r) / 2 > pair) --r;
        if ((r + 1) * (63 - (r + 1)) / 2 <= pair) ++r;
    }
    const int c = r + 1 + (pair - r * (63 - r) / 2);

    __shared__ __align__(16) float Otile[256][4];

    // ---- A fragments: lane holds K_p[i = nt*16+col][j = ks*32 + quad*8 + t] ----
    bf16x8 kfr[4][2];
    if (PRE) {
        const unsigned short* kb = (const unsigned short*)kernP + (size_t)pair * 4096;
        #pragma unroll
        for (int nt = 0; nt < 4; ++nt)
            #pragma unroll
            for (int ks = 0; ks < 2; ++ks)
                kfr[nt][ks] = *(const bf16x8*)(kb + (nt*2 + ks) * 512 + col * 32 + quad * 8);
    } else {
        const float* kf = (const float*)kernP;
        #pragma unroll
        for (int nt = 0; nt < 4; ++nt)
            #pragma unroll
            for (int ks = 0; ks < 2; ++ks)
                kfr[nt][ks] = cvt8(kf + (size_t)(nt*16 + col) * (NPAIRS*EMBED)
                                     + (size_t)pair * EMBED + ks*32 + quad*8);
    }

    float res[16];

    #pragma unroll
    for (int it = 0; it < 16; ++it) {
        const int brow = bt * 256 + it * 16 + col;

        bf16x8 bfr0, bfr1;
        ushort4 qv[4];
        if (PRE) {
            const unsigned short* er = (const unsigned short*)embP
                                     + ((size_t)r * BATCH + brow) * EMBED;
            bfr0 = *(const bf16x8*)(er + quad*8);
            bfr1 = *(const bf16x8*)(er + 32 + quad*8);
            const unsigned short* ec = (const unsigned short*)embP
                                     + ((size_t)c * BATCH + brow) * EMBED;
            #pragma unroll
            for (int nt = 0; nt < 4; ++nt)
                qv[nt] = *(const ushort4*)(ec + nt*16 + quad*4);
        } else {
            const float* ef = (const float*)embP + ((size_t)brow * NFIELDS + r) * EMBED;
            bfr0 = cvt8(ef + quad*8);
            bfr1 = cvt8(ef + 32 + quad*8);
            const float* qp = embF + ((size_t)brow * NFIELDS + c) * EMBED + quad*4;
            #pragma unroll
            for (int nt = 0; nt < 4; ++nt) {
                f32x4 q = *(const f32x4*)(qp + nt*16);
                qv[nt].x = f2bf(q[0]); qv[nt].y = f2bf(q[1]);
                qv[nt].z = f2bf(q[2]); qv[nt].w = f2bf(q[3]);
            }
        }

        float partial = 0.f;
        #pragma unroll
        for (int nt = 0; nt < 4; ++nt) {
            f32x4 acc = {0.f, 0.f, 0.f, 0.f};
            acc = __builtin_amdgcn_mfma_f32_16x16x32_bf16(kfr[nt][0], bfr0, acc, 0, 0, 0);
            acc = __builtin_amdgcn_mfma_f32_16x16x32_bf16(kfr[nt][1], bfr1, acc, 0, 0, 0);
            partial += acc[0]*bf2f(qv[nt].x) + acc[1]*bf2f(qv[nt].y)
                     + acc[2]*bf2f(qv[nt].z) + acc[3]*bf2f(qv[nt].w);
        }
        // reduce over i: lanes {col, col+16, col+32, col+48}
        partial += __shfl_xor(partial, 16, 64);
        partial += __shfl_xor(partial, 32, 64);
        res[it] = partial;
    }

    if (quad == 0) {
        #pragma unroll
        for (int it = 0; it < 16; ++it)
            Otile[it*16 + col][wave] = res[it];
    }
    __syncthreads();

    {
        f32x4 o = *(const f32x4*)&Otile[tid][0];
        *(f32x4*)&out[((size_t)(bt*256 + tid)) * NPAIRS + chunk*4] = o;
    }
}

extern "C" void kernel_launch(void* const* d_in, const int* in_sizes, int n_in,
                              void* d_out, int out_size, void* d_ws, size_t ws_size,
                              hipStream_t stream) {
    const float* emb  = (const float*)d_in[0];   // (2048, 32, 64) fp32
    const float* kern = (const float*)d_in[1];   // (64, 496, 64) fp32
    float* out = (float*)d_out;                  // (2048, 1, 496) fp32

    const size_t embElems  = (size_t)BATCH * NFIELDS * EMBED;   // 4194304
    const size_t kernElems = (size_t)EMBED * NPAIRS * EMBED;    // 2031616
    const size_t need = (embElems + kernElems) * sizeof(unsigned short);

    if (ws_size >= need) {
        unsigned short* embT  = (unsigned short*)d_ws;
        unsigned short* kernB = embT + embElems;
        int total4 = (int)((embElems + kernElems) / 4);         // 1556480
        convert_prepass<<<(total4 + 255) / 256, 256, 0, stream>>>(emb, kern, embT, kernB);
        opn_fused<true><<<dim3(992), 256, 0, stream>>>(
            (const void*)embT, (const void*)kernB, emb, out);
    } else {
        opn_fused<false><<<dim3(992), 256, 0, stream>>>(
            (const void*)emb, (const void*)kern, emb, out);
    }
}

// Round 23
// 120.290 us; speedup vs baseline: 1.0072x; 1.0072x over previous
//
#include <hip/hip_runtime.h>
#include <hip/hip_bf16.h>
#include <math.h>

#define BATCH   2048
#define NFIELDS 32
#define EMBED   64
#define NPAIRS  496

typedef __attribute__((ext_vector_type(8))) short bf16x8;
typedef __attribute__((ext_vector_type(4))) float f32x4;

__device__ __forceinline__ unsigned short f2bf(float x) {
    unsigned int u = __float_as_uint(x);
    unsigned int r = 0x7fffu + ((u >> 16) & 1u);
    return (unsigned short)((u + r) >> 16);
}
__device__ __forceinline__ float bf2f(unsigned short b) {
    return __uint_as_float(((unsigned int)b) << 16);
}
__device__ __forceinline__ bf16x8 cvt8(const float* p) {
    float4 v0 = *(const float4*)p;
    float4 v1 = *(const float4*)(p + 4);
    bf16x8 o;
    o[0]=(short)f2bf(v0.x); o[1]=(short)f2bf(v0.y); o[2]=(short)f2bf(v0.z); o[3]=(short)f2bf(v0.w);
    o[4]=(short)f2bf(v1.x); o[5]=(short)f2bf(v1.y); o[6]=(short)f2bf(v1.z); o[7]=(short)f2bf(v1.w);
    return o;
}

// Prepass with TRANSPOSE (R22-proven): embT[f][b][j] bf16 (batch fast axis);
// K' [p][blk=nt*2+ks][col][quad][8] bf16 (fragment-ordered, kfr coalesced).
__global__ __launch_bounds__(256) void convert_prepass(
    const float* __restrict__ emb, const float* __restrict__ kern,
    unsigned short* __restrict__ embT, unsigned short* __restrict__ kernB)
{
    const int EMBT4 = BATCH * NFIELDS * EMBED / 4;  // 1048576
    const int KER4  = EMBED * NPAIRS * EMBED / 4;   // 507904
    int t = blockIdx.x * blockDim.x + threadIdx.x;
    if (t < EMBT4) {
        int j4   = t & 15;
        int rest = t >> 4;
        int b = rest & 2047;
        int f = rest >> 11;
        float4 v = *(const float4*)(emb + ((size_t)b * NFIELDS + f) * EMBED + j4 * 4);
        ushort4 o;
        o.x = f2bf(v.x); o.y = f2bf(v.y); o.z = f2bf(v.z); o.w = f2bf(v.w);
        *(ushort4*)(embT + (size_t)t * 4) = o;
    } else if (t < EMBT4 + KER4) {
        int u = t - EMBT4;
        int g    = u & 1;
        int quad = (u >> 1) & 3;
        int col  = (u >> 3) & 15;
        int blk  = (u >> 7) & 7;
        int p    = u >> 10;
        int i = (blk >> 1) * 16 + col;
        int j = (blk & 1) * 32 + quad * 8 + g * 4;
        float4 v = *(const float4*)(kern + (size_t)i * (NPAIRS*EMBED) + (size_t)p * EMBED + j);
        ushort4 o;
        o.x = f2bf(v.x); o.y = f2bf(v.y); o.z = f2bf(v.z); o.w = f2bf(v.w);
        *(ushort4*)(kernB + (size_t)u * 4) = o;
    }
}

// Main: 1984 blocks = 124 chunks x 16 batch-tiles(128). Wave w owns pair chunk*4+w,
// 8 iterations of 16 batches. R18-proven DMA double-buffer stages ONLY the r-field
// (seg-major LDS, counted vmcnt); q read DIRECT from transposed embT with a named
// qA/qB ping-pong issued one iter ahead (static after unroll -> stays in regs,
// not sunk). LDS 18KB -> 6 blocks/CU at launch_bounds(256,6) = 24 waves/CU
// (1.5x R18's TLP). vmcnt ledger: iters issue 2 DMA + 4 q loads; vmcnt(6)
// retires buffer `it` + q(it); last iter vmcnt(0).
template<bool PRE>
__global__ __launch_bounds__(256, 6) void opn_fused(
    const void* __restrict__ embP, const void* __restrict__ kernP,
    const float* __restrict__ embF, float* __restrict__ out)
{
    const int bid   = blockIdx.x;
    const int chunk = bid >> 4;            // 0..123
    const int bt    = bid & 15;            // 0..15

    const int tid  = threadIdx.x;
    const int wave = tid >> 6, lane = tid & 63;
    const int col  = lane & 15, quad = lane >> 4;
    const int pair = chunk * 4 + wave;

    // closed-form triu k=1 decode (R12-proven)
    int r;
    {
        float sq = sqrtf((float)(3969 - 8 * pair));   // 3969 = 63^2
        r = (int)((63.0f - sq) * 0.5f);
        if (r > 0 && r * (63 - r) / 2 > pair) --r;
        if ((r + 1) * (63 - (r + 1)) / 2 <= pair) ++r;
    }
    const int c = r + 1 + (pair - r * (63 - r) / 2);

    __shared__ __align__(16) unsigned short Stage[4][2][1024]; // [wave][buf][2KB r-tile]
    __shared__ __align__(16) float Otile[128][4];

    // ---- A fragments: lane holds K_p[i = nt*16+col][j = ks*32 + quad*8 + t] ----
    bf16x8 kfr[4][2];
    if (PRE) {
        const unsigned short* kb = (const unsigned short*)kernP + (size_t)pair * 4096;
        #pragma unroll
        for (int nt = 0; nt < 4; ++nt)
            #pragma unroll
            for (int ks = 0; ks < 2; ++ks)
                kfr[nt][ks] = *(const bf16x8*)(kb + (nt*2 + ks) * 512 + col * 32 + quad * 8);
    } else {
        const float* kf = (const float*)kernP;
        #pragma unroll
        for (int nt = 0; nt < 4; ++nt)
            #pragma unroll
            for (int ks = 0; ks < 2; ++ks)
                kfr[nt][ks] = cvt8(kf + (size_t)(nt*16 + col) * (NPAIRS*EMBED)
                                     + (size_t)pair * EMBED + ks*32 + quad*8);
    }

    if (PRE) {
        const unsigned short* eb = (const unsigned short*)embP;  // embT[f][b][j]
        const int rr = lane & 15;
        const int ss = lane >> 4;
        const int brow0 = bt * 128;
        const unsigned short* gr = eb + ((size_t)r * BATCH + brow0 + rr) * EMBED + ss*8;
        const unsigned short* ecb = eb + ((size_t)c * BATCH + brow0 + col) * EMBED;
        const size_t itstride = (size_t)16 * EMBED;   // 16 batch rows in embT

        const unsigned offB0 = (unsigned)quad * 256 + (unsigned)col * 16;
        const unsigned offB1 = offB0 + 1024;

        #define STAGE(itv, bufv) do {                                                     \
            const unsigned short* _r = gr + (size_t)(itv) * itstride;                     \
            __builtin_amdgcn_global_load_lds(                                             \
                (const __attribute__((address_space(1))) void*)_r,                        \
                (__attribute__((address_space(3))) void*)&Stage[wave][bufv][0],   16, 0, 0); \
            __builtin_amdgcn_global_load_lds(                                             \
                (const __attribute__((address_space(1))) void*)(_r + 32),                 \
                (__attribute__((address_space(3))) void*)&Stage[wave][bufv][512], 16, 0, 0); \
        } while (0)

        #define LOADQ(dst, itv) do {                                                      \
            const unsigned short* _e = ecb + (size_t)(itv) * itstride;                    \
            dst##0 = *(const ushort4*)(_e + 0*16 + quad*4);                               \
            dst##1 = *(const ushort4*)(_e + 1*16 + quad*4);                               \
            dst##2 = *(const ushort4*)(_e + 2*16 + quad*4);                               \
            dst##3 = *(const ushort4*)(_e + 3*16 + quad*4);                               \
        } while (0)

        ushort4 qA0, qA1, qA2, qA3, qB0, qB1, qB2, qB3;
        STAGE(0, 0);
        LOADQ(qA, 0);

        #pragma unroll
        for (int it = 0; it < 8; ++it) {
            const int buf = it & 1;
            if (it < 7) {
                STAGE(it + 1, buf ^ 1);
                if ((it & 1) == 0) { LOADQ(qB, it + 1); }
                else               { LOADQ(qA, it + 1); }
                asm volatile("s_waitcnt vmcnt(6)" ::: "memory");  // buf `it` + q(it) done
            } else {
                asm volatile("s_waitcnt vmcnt(0)" ::: "memory");
            }
            __builtin_amdgcn_sched_barrier(0);

            const char* rb = (const char*)&Stage[wave][buf][0];
            bf16x8 bfr0 = *(const bf16x8*)(rb + offB0);
            bf16x8 bfr1 = *(const bf16x8*)(rb + offB1);

            float partial = 0.f;
            #pragma unroll
            for (int nt = 0; nt < 4; ++nt) {
                f32x4 acc = {0.f, 0.f, 0.f, 0.f};
                acc = __builtin_amdgcn_mfma_f32_16x16x32_bf16(kfr[nt][0], bfr0, acc, 0, 0, 0);
                acc = __builtin_amdgcn_mfma_f32_16x16x32_bf16(kfr[nt][1], bfr1, acc, 0, 0, 0);
                ushort4 qv;
                if ((it & 1) == 0) qv = (nt == 0) ? qA0 : (nt == 1) ? qA1 : (nt == 2) ? qA2 : qA3;
                else               qv = (nt == 0) ? qB0 : (nt == 1) ? qB1 : (nt == 2) ? qB2 : qB3;
                partial += acc[0]*bf2f(qv.x) + acc[1]*bf2f(qv.y)
                         + acc[2]*bf2f(qv.z) + acc[3]*bf2f(qv.w);
            }
            partial += __shfl_xor(partial, 16, 64);
            partial += __shfl_xor(partial, 32, 64);
            if (quad == 0) Otile[it*16 + col][wave] = partial;
        }
        #undef STAGE
        #undef LOADQ
    } else {
        // fallback: direct fp32 path (R12/R22-proven)
        #pragma unroll
        for (int it = 0; it < 8; ++it) {
            const int brow = bt * 128 + it * 16 + col;
            const float* ef = (const float*)embP + ((size_t)brow * NFIELDS + r) * EMBED;
            bf16x8 bfr0 = cvt8(ef + quad*8);
            bf16x8 bfr1 = cvt8(ef + 32 + quad*8);
            const float* qp = embF + ((size_t)brow * NFIELDS + c) * EMBED + quad*4;
            float partial = 0.f;
            #pragma unroll
            for (int nt = 0; nt < 4; ++nt) {
                f32x4 q = *(const f32x4*)(qp + nt*16);
                f32x4 acc = {0.f, 0.f, 0.f, 0.f};
                acc = __builtin_amdgcn_mfma_f32_16x16x32_bf16(kfr[nt][0], bfr0, acc, 0, 0, 0);
                acc = __builtin_amdgcn_mfma_f32_16x16x32_bf16(kfr[nt][1], bfr1, acc, 0, 0, 0);
                partial += acc[0]*q[0] + acc[1]*q[1] + acc[2]*q[2] + acc[3]*q[3];
            }
            partial += __shfl_xor(partial, 16, 64);
            partial += __shfl_xor(partial, 32, 64);
            if (quad == 0) Otile[it*16 + col][wave] = partial;
        }
    }

    __syncthreads();

    if (tid < 128) {
        f32x4 o = *(const f32x4*)&Otile[tid][0];
        *(f32x4*)&out[((size_t)(bt*128 + tid)) * NPAIRS + chunk*4] = o;
    }
}

extern "C" void kernel_launch(void* const* d_in, const int* in_sizes, int n_in,
                              void* d_out, int out_size, void* d_ws, size_t ws_size,
                              hipStream_t stream) {
    const float* emb  = (const float*)d_in[0];   // (2048, 32, 64) fp32
    const float* kern = (const float*)d_in[1];   // (64, 496, 64) fp32
    float* out = (float*)d_out;                  // (2048, 1, 496) fp32

    const size_t embElems  = (size_t)BATCH * NFIELDS * EMBED;   // 4194304
    const size_t kernElems = (size_t)EMBED * NPAIRS * EMBED;    // 2031616
    const size_t need = (embElems + kernElems) * sizeof(unsigned short);

    if (ws_size >= need) {
        unsigned short* embT  = (unsigned short*)d_ws;
        unsigned short* kernB = embT + embElems;
        int total4 = (int)((embElems + kernElems) / 4);         // 1556480
        convert_prepass<<<(total4 + 255) / 256, 256, 0, stream>>>(emb, kern, embT, kernB);
        opn_fused<true><<<dim3(1984), 256, 0, stream>>>(
            (const void*)embT, (const void*)kernB, emb, out);
    } else {
        opn_fused<false><<<dim3(1984), 256, 0, stream>>>(
            (const void*)emb, (const void*)kern, emb, out);
    }
}